// Round 3
// baseline (1722.774 us; speedup 1.0000x reference)
//
#include <hip/hip_runtime.h>
#include <math.h>

#define TSTEPS 32
#define CAPL 33
#define EDIM 512
#define HDIM 512
#define VOCAB 10000
#define BATCH 64
#define RREG 49

// ---------- fast transcendentals (v_exp_f32 / v_rcp_f32 based) ----------
__device__ __forceinline__ float frcp(float x) { return __builtin_amdgcn_rcpf(x); }
__device__ __forceinline__ float ftanh(float x) {
  // tanh(x) = 1 - 2/(exp(2x)+1); saturates correctly for |x| large
  float e = __expf(2.f * x);
  return 1.f - 2.f * frcp(e + 1.f);
}
__device__ __forceinline__ float fsig(float x) {
  return frcp(1.f + __expf(-x));
}

// ================= big-tile fp32 GEMM (prologue + vocab projection) =================
// C[m,n] = sum_k A[m,k]*B(k,n) (+bias[n]) (+D[m,n])
// BT: B stored [n][k] row-major. GATHER: A row = caps[(m>>5)*CAPL + (m&31)].
struct GemmP {
  const float* A; const float* B; const float* bias; const float* D;
  float* C; int M, N, K, lda, ldb, ldd, ldc;
  const int* caps;
};

template<bool BT, bool GATHER>
__device__ __forceinline__ void gemm_body(GemmP p, int bx, int by)
{
  __shared__ float as[32][132];
  __shared__ float bs[32][132];
  const int tid = threadIdx.x;
  const int m0 = by * 128, n0 = bx * 128;
  const int tx = tid & 15, ty = tid >> 4;
  float acc[8][8];
#pragma unroll
  for (int i = 0; i < 8; ++i)
#pragma unroll
    for (int j = 0; j < 8; ++j) acc[i][j] = 0.f;

  const int lr = tid >> 3, lf = tid & 7;   // loader for A and B^T tiles
  const int nf = tid & 31, nk = tid >> 5;  // loader for B NN tiles

  for (int k0 = 0; k0 < p.K; k0 += 32) {
    // ---- stage A tile (transposed to as[k][m]) ----
#pragma unroll
    for (int q = 0; q < 4; ++q) {
      int m = m0 + lr + 32 * q;
      float4 v = make_float4(0.f, 0.f, 0.f, 0.f);
      if (m < p.M) {
        int row = m;
        if (GATHER) row = p.caps[(m >> 5) * CAPL + (m & 31)];
        v = *(const float4*)(p.A + (size_t)row * p.lda + k0 + lf * 4);
      }
      int rr = lr + 32 * q;
      as[lf * 4 + 0][rr] = v.x; as[lf * 4 + 1][rr] = v.y;
      as[lf * 4 + 2][rr] = v.z; as[lf * 4 + 3][rr] = v.w;
    }
    // ---- stage B tile into bs[k][n] ----
    if (BT) {
#pragma unroll
      for (int q = 0; q < 4; ++q) {
        int n = n0 + lr + 32 * q;
        float4 v = make_float4(0.f, 0.f, 0.f, 0.f);
        if (n < p.N) v = *(const float4*)(p.B + (size_t)n * p.ldb + k0 + lf * 4);
        int rr = lr + 32 * q;
        bs[lf * 4 + 0][rr] = v.x; bs[lf * 4 + 1][rr] = v.y;
        bs[lf * 4 + 2][rr] = v.z; bs[lf * 4 + 3][rr] = v.w;
      }
    } else {
#pragma unroll
      for (int q = 0; q < 4; ++q) {
        int k = nk + 8 * q;
        int n = n0 + nf * 4;
        float4 v = make_float4(0.f, 0.f, 0.f, 0.f);
        if (n < p.N) v = *(const float4*)(p.B + (size_t)(k0 + k) * p.ldb + n);
        *(float4*)&bs[k][nf * 4] = v;
      }
    }
    __syncthreads();
#pragma unroll
    for (int k = 0; k < 32; ++k) {
      float4 a0 = *(const float4*)&as[k][ty * 4];
      float4 a1 = *(const float4*)&as[k][ty * 4 + 64];
      float4 b0 = *(const float4*)&bs[k][tx * 4];
      float4 b1 = *(const float4*)&bs[k][tx * 4 + 64];
      float av[8] = {a0.x, a0.y, a0.z, a0.w, a1.x, a1.y, a1.z, a1.w};
      float bv[8] = {b0.x, b0.y, b0.z, b0.w, b1.x, b1.y, b1.z, b1.w};
#pragma unroll
      for (int i = 0; i < 8; ++i)
#pragma unroll
        for (int j = 0; j < 8; ++j)
          acc[i][j] = fmaf(av[i], bv[j], acc[i][j]);
    }
    __syncthreads();
  }
  // ---- epilogue ----
  const bool hb = (p.bias != nullptr);
  const bool hd = (p.D != nullptr);
#pragma unroll
  for (int i = 0; i < 8; ++i) {
    int m = m0 + ty * 4 + (i & 3) + ((i >> 2) * 64);
    if (m >= p.M) continue;
#pragma unroll
    for (int jj = 0; jj < 2; ++jj) {
      int n = n0 + tx * 4 + jj * 64;
      if (n >= p.N) continue;  // N % 4 == 0 for all shapes here
      float4 r;
      r.x = acc[i][jj * 4 + 0]; r.y = acc[i][jj * 4 + 1];
      r.z = acc[i][jj * 4 + 2]; r.w = acc[i][jj * 4 + 3];
      if (hb) { r.x += p.bias[n]; r.y += p.bias[n + 1]; r.z += p.bias[n + 2]; r.w += p.bias[n + 3]; }
      if (hd) {
        const float4 d = *(const float4*)(p.D + (size_t)m * p.ldd + n);
        r.x += d.x; r.y += d.y; r.z += d.z; r.w += d.w;
      }
      *(float4*)(p.C + (size_t)m * p.ldc + n) = r;
    }
  }
}

template<bool BT, bool GATHER>
__global__ __launch_bounds__(256) void gemm_k(GemmP p) {
  gemm_body<BT, GATHER>(p, blockIdx.x, blockIdx.y);
}

// fused prologue: z=0 -> gxx GEMM (gather, BT), z=1 -> fproj GEMM (NN)
__global__ __launch_bounds__(256) void k_prologue(GemmP pk1, GemmP pk0) {
  if (blockIdx.z == 0) {
    if (blockIdx.x < 12 && blockIdx.y < 16) gemm_body<true, true>(pk1, blockIdx.x, blockIdx.y);
  } else {
    if (blockIdx.x < 4 && blockIdx.y < 25) gemm_body<false, false>(pk0, blockIdx.x, blockIdx.y);
  }
}

// ================= skinny gates GEMM: P[64,3072] = [ctx@Wc^T | h@Whh^T] =================
// 64x64 tile, 256 threads (4x4 micro), split-K=2 via blockIdx.z. Pure partial products;
// bias/gxx/partial-sum folded into the consumer (k_front).
struct GateP {
  const float* ctx; const float* h;   // each 64x512 (h == nullptr at t==0)
  const float* Wc;  const float* Wh;  // [1536][k] row-major, ld 1024 / 512
  float* P;                           // [2][64][3072]
};

__global__ __launch_bounds__(256) void k_gates(GateP g)
{
  __shared__ float as[32][68];
  __shared__ float bs[32][68];
  const int tid = threadIdx.x;
  const int n0g = blockIdx.x * 64;            // 0..3071
  const bool hh = (n0g >= 1536);
  const float* A = hh ? g.h : g.ctx;
  const float* B = hh ? g.Wh : g.Wc;
  const int ldb = hh ? 512 : 1024;
  const int nb = hh ? (n0g - 1536) : n0g;
  const int kbase = blockIdx.z * 256;
  float* C = g.P + (size_t)blockIdx.z * 64 * 3072;

  const int tx = tid & 15, ty = tid >> 4;
  float acc[4][4] = {};
  if (A != nullptr) {
    const int lr = tid >> 3, lf = tid & 7;    // lr 0..31, lf 0..7
    for (int k0 = kbase; k0 < kbase + 256; k0 += 32) {
      {
        float4 v = *(const float4*)(A + (size_t)lr * 512 + k0 + lf * 4);
        as[lf * 4 + 0][lr] = v.x; as[lf * 4 + 1][lr] = v.y;
        as[lf * 4 + 2][lr] = v.z; as[lf * 4 + 3][lr] = v.w;
        float4 w = *(const float4*)(A + (size_t)(lr + 32) * 512 + k0 + lf * 4);
        as[lf * 4 + 0][lr + 32] = w.x; as[lf * 4 + 1][lr + 32] = w.y;
        as[lf * 4 + 2][lr + 32] = w.z; as[lf * 4 + 3][lr + 32] = w.w;
      }
      {
        float4 v = *(const float4*)(B + (size_t)(nb + lr) * ldb + k0 + lf * 4);
        bs[lf * 4 + 0][lr] = v.x; bs[lf * 4 + 1][lr] = v.y;
        bs[lf * 4 + 2][lr] = v.z; bs[lf * 4 + 3][lr] = v.w;
        float4 w = *(const float4*)(B + (size_t)(nb + lr + 32) * ldb + k0 + lf * 4);
        bs[lf * 4 + 0][lr + 32] = w.x; bs[lf * 4 + 1][lr + 32] = w.y;
        bs[lf * 4 + 2][lr + 32] = w.z; bs[lf * 4 + 3][lr + 32] = w.w;
      }
      __syncthreads();
#pragma unroll
      for (int k = 0; k < 32; ++k) {
        float4 a = *(const float4*)&as[k][ty * 4];
        float4 b = *(const float4*)&bs[k][tx * 4];
        float av[4] = {a.x, a.y, a.z, a.w};
        float bv[4] = {b.x, b.y, b.z, b.w};
#pragma unroll
        for (int i = 0; i < 4; ++i)
#pragma unroll
          for (int j = 0; j < 4; ++j)
            acc[i][j] = fmaf(av[i], bv[j], acc[i][j]);
      }
      __syncthreads();
    }
  }
#pragma unroll
  for (int i = 0; i < 4; ++i) {
    float4 r = make_float4(acc[i][0], acc[i][1], acc[i][2], acc[i][3]);
    *(float4*)(C + (size_t)(ty * 4 + i) * 3072 + n0g + tx * 4) = r;
  }
}

// ================= fused per-step front: GRU update + hproj GEMV + attention =================
// block b (64 blocks) x 512 threads. t == TSTEPS: update only (final h -> hall[31]).
__global__ __launch_bounds__(512) void k_front(
    const float* __restrict__ P,     // [2][64][3072] split-K partials from step t-1
    const float* __restrict__ gxx,   // [B*T][1536] x-part pre-gates (incl b_ih)
    const float* __restrict__ bhh,   // [1536]
    float* __restrict__ h,           // [64][512]
    float* __restrict__ hall,        // [B*T][512]
    const float* __restrict__ fproj, // [B*R][512]
    const float* __restrict__ features, // [B*R][512]
    const float* __restrict__ vw,    // [512]
    const float* __restrict__ aw2,   // attn_W + E*H, [512][512]
    float* __restrict__ ctx,         // [64][512]
    int t)
{
  __shared__ float hs[512];
  __shared__ float hp[512];
  __shared__ float sc[64];
  const int b = blockIdx.x, j = threadIdx.x;

  // --- phase 1: GRU update (h_{t-1} -> h_t), record into hall[t-1] ---
  if (t > 0) {
    const float* p0 = P + (size_t)b * 3072;
    const float* p1 = P + (size_t)64 * 3072 + (size_t)b * 3072;
    const float* gx = gxx + ((size_t)b * TSTEPS + (t - 1)) * 1536;
    float xr = p0[j]        + p1[j]        + gx[j];
    float xz = p0[512 + j]  + p1[512 + j]  + gx[512 + j];
    float xn = p0[1024 + j] + p1[1024 + j] + gx[1024 + j];
    float hr = p0[1536 + j] + p1[1536 + j] + bhh[j];
    float hz = p0[2048 + j] + p1[2048 + j] + bhh[512 + j];
    float hn = p0[2560 + j] + p1[2560 + j] + bhh[1024 + j];
    float hold = (t == 1) ? 0.f : h[b * 512 + j];
    float r = fsig(xr + hr);
    float z = fsig(xz + hz);
    float n = ftanh(xn + r * hn);
    float hv = (1.f - z) * n + z * hold;
    h[b * 512 + j] = hv;
    hall[((size_t)b * TSTEPS + (t - 1)) * 512 + j] = hv;
    hs[j] = hv;
  } else {
    hs[j] = 0.f;
  }
  if (t == TSTEPS) return;   // final step: update only (uniform exit)
  if (j >= RREG && j < 64) sc[j] = -1e30f;
  __syncthreads();

  // --- phase 2: hproj[j] = sum_k h[k] * aw2[k][j] (coalesced over j) ---
  float hpv = 0.f;
  if (t > 0) {
    float a0 = 0.f, a1 = 0.f, a2 = 0.f, a3 = 0.f;
    for (int k = 0; k < 512; k += 4) {
      a0 = fmaf(hs[k + 0], aw2[(size_t)(k + 0) * 512 + j], a0);
      a1 = fmaf(hs[k + 1], aw2[(size_t)(k + 1) * 512 + j], a1);
      a2 = fmaf(hs[k + 2], aw2[(size_t)(k + 2) * 512 + j], a2);
      a3 = fmaf(hs[k + 3], aw2[(size_t)(k + 3) * 512 + j], a3);
    }
    hpv = (a0 + a1) + (a2 + a3);
  }
  hp[j] = hpv;
  __syncthreads();

  // --- phase 3: scores[r] = sum_h vw[h]*tanh(fproj[b,r,h] + hp[h]) ---
  const int wv = j >> 6, lane = j & 63;
  float vwr[8], hpr[8];
#pragma unroll
  for (int c = 0; c < 8; ++c) {
    vwr[c] = vw[lane + 64 * c];
    hpr[c] = hp[lane + 64 * c];
  }
  const float* fpb = fproj + (size_t)b * RREG * 512;
  for (int i = 0; i < 7; ++i) {
    int r = wv + 8 * i;
    if (r < RREG) {
      float s = 0.f;
#pragma unroll
      for (int c = 0; c < 8; ++c)
        s += vwr[c] * ftanh(fpb[r * 512 + lane + 64 * c] + hpr[c]);
#pragma unroll
      for (int d = 32; d > 0; d >>= 1) s += __shfl_xor(s, d, 64);
      if (lane == 0) sc[r] = s;
    }
  }
  __syncthreads();

  // --- phase 4: softmax over r (wave 0) ---
  if (wv == 0) {
    float v = sc[lane];
    float m = v;
#pragma unroll
    for (int d = 32; d > 0; d >>= 1) m = fmaxf(m, __shfl_xor(m, d, 64));
    float e = (lane < RREG) ? __expf(v - m) : 0.f;
    float ssum = e;
#pragma unroll
    for (int d = 32; d > 0; d >>= 1) ssum += __shfl_xor(ssum, d, 64);
    sc[lane] = e * frcp(ssum);
  }
  __syncthreads();

  // --- phase 5: ctx[b,e] = sum_r attn[r]*features[b,r,e] ---
  float a = 0.f;
  const float* fb = features + (size_t)b * RREG * 512;
  for (int r = 0; r < RREG; ++r) a = fmaf(sc[r], fb[r * 512 + j], a);
  ctx[b * 512 + j] = a;
}

extern "C" void kernel_launch(void* const* d_in, const int* in_sizes, int n_in,
                              void* d_out, int out_size, void* d_ws, size_t ws_size,
                              hipStream_t stream)
{
  const float* features = (const float*)d_in[0];
  const int*   captions = (const int*)d_in[1];
  const float* embed    = (const float*)d_in[2];
  const float* attn_W   = (const float*)d_in[3];
  const float* attn_b   = (const float*)d_in[4];
  const float* v_w      = (const float*)d_in[5];
  const float* W_ih     = (const float*)d_in[6];
  const float* W_hh     = (const float*)d_in[7];
  const float* b_ih     = (const float*)d_in[8];
  const float* b_hh     = (const float*)d_in[9];
  const float* fc_W     = (const float*)d_in[10];
  const float* fc_b     = (const float*)d_in[11];
  float* out = (float*)d_out;

  float* ws = (float*)d_ws;
  float* gxx   = ws; ws += (size_t)2048 * 1536;  // [b*T+t][3H] x-part pre-gates (+b_ih)
  float* fproj = ws; ws += (size_t)3136 * 512;   // [b*R+r][H]
  float* hbuf  = ws; ws += 64 * 512;             // h_t
  float* ctxb  = ws; ws += 64 * 512;             // context
  float* P     = ws; ws += (size_t)2 * 64 * 3072;// split-K partial pre-gates
  float* hall  = ws; ws += (size_t)2048 * 512;   // all h_t (fc GEMM A)

  // fused prologue: gxx = embed[captions]@W_ih[:,:E]^T + b_ih ; fproj = features@attn_W[:E] + attn_b
  {
    GemmP p1{embed, W_ih, b_ih, nullptr, gxx, 2048, 1536, 512, 512, 1024, 0, 1536, captions};
    GemmP p0{features, attn_W, attn_b, nullptr, fproj, 3136, 512, 512, 512, 512, 0, 512, nullptr};
    k_prologue<<<dim3(12, 25, 2), 256, 0, stream>>>(p1, p0);
  }

  for (int t = 0; t < TSTEPS; ++t) {
    k_front<<<64, 512, 0, stream>>>(P, gxx, b_hh, hbuf, hall, fproj, features,
                                    v_w, attn_W + (size_t)EDIM * HDIM, ctxb, t);
    GateP g{ctxb, (t == 0) ? nullptr : hbuf, W_ih + EDIM, W_hh, P};
    k_gates<<<dim3(48, 1, 2), 256, 0, stream>>>(g);
  }
  // final update (t == TSTEPS): h_31 -> h_32 -> hall[31]
  k_front<<<64, 512, 0, stream>>>(P, gxx, b_hh, hbuf, hall, fproj, features,
                                  v_w, attn_W + (size_t)EDIM * HDIM, ctxb, TSTEPS);

  // vocab projection: out = hall @ fc_W + fc_b  (2048 x 10000 x 512)
  {
    GemmP p{hall, fc_W, fc_b, nullptr, out, 2048, 10000, 512, 512, 10000, 0, 10000, nullptr};
    gemm_k<false, false><<<dim3(79, 16), 256, 0, stream>>>(p);
  }
}